// Round 8
// baseline (194.080 us; speedup 1.0000x reference)
//
#include <hip/hip_runtime.h>
#include <math.h>

#define TPB 128   // 2 waves/block: 16 blocks/CU (HW cap) = 32 waves = 100% of wave cap

// native clang vector type accepted by __builtin_nontemporal_store
typedef float nt_float4 __attribute__((ext_vector_type(4)));

// R = I + a*K + b*K^2 with K=skew(v), K^2 = v v^T - th^2 I
// => R = (1 - b*th^2) I + b * v v^T + a * K   (matches reference incl. small-angle branch)
__device__ __forceinline__ void rodrigues(float v0, float v1, float v2, float R[9]) {
    float th2 = v0 * v0 + v1 * v1 + v2 * v2;
    float th  = sqrtf(th2);
    float s, c;
    sincosf(th, &s, &c);
    bool  sm = th < 1e-6f;
    float a  = sm ? 1.0f : s / th;
    float b  = sm ? 0.5f : (1.0f - c) / th2;
    float cc = 1.0f - b * th2;
    R[0] = cc + b * v0 * v0;      R[1] = b * v0 * v1 - a * v2;  R[2] = b * v0 * v2 + a * v1;
    R[3] = b * v0 * v1 + a * v2;  R[4] = cc + b * v1 * v1;      R[5] = b * v1 * v2 - a * v0;
    R[6] = b * v0 * v2 - a * v1;  R[7] = b * v1 * v2 + a * v0;  R[8] = cc + b * v2 * v2;
}

__device__ __forceinline__ void nt_store4(float4* p, float x, float y, float z, float w) {
    nt_float4 v = { x, y, z, w };
    __builtin_nontemporal_store(v, (nt_float4*)p);
}

// One 128-element tile per block; 15,625 blocks (2,000,000 % 128 == 0, no tail).
// Input: LDS-staged coalesced float4 (96 threads x 1 float4 per array).
// Output: direct per-thread 3x float4 at 48-B lane stride (proven non-amplifying in R5),
// marked NONTEMPORAL so the 94-MB output stream doesn't evict the 96-MB input set
// from the 256-MB LLC -> inputs stay LLC-resident, FETCH_SIZE should collapse.
__global__ __launch_bounds__(TPB) void aff_kernel(
    const float4* __restrict__ trans,
    const float4* __restrict__ rotat,
    const float4* __restrict__ sdir,
    const float4* __restrict__ scal,
    float4* __restrict__ out,
    int B)
{
    __shared__ float s_in[4][TPB * 3];   // 6 KB: 384 floats per input array

    const int tid  = threadIdx.x;
    const int base = blockIdx.x * TPB;           // first element of this block
    const int n    = min(TPB, B - base);         // elements in this block
    const int nf4  = (n * 3) >> 2;               // float4s per input (96 for full tile)

    // ---- coalesced global -> LDS: 96 consecutive float4 per input ----
    if (tid < nf4) {
        const int gbase = (base * 3) >> 2;       // = blockIdx.x * 96
        float4 a = trans[gbase + tid];
        float4 b = rotat[gbase + tid];
        float4 c = sdir [gbase + tid];
        float4 d = scal [gbase + tid];
        ((float4*)&s_in[0][0])[tid] = a;
        ((float4*)&s_in[1][0])[tid] = b;
        ((float4*)&s_in[2][0])[tid] = c;
        ((float4*)&s_in[3][0])[tid] = d;
    }
    __syncthreads();

    // ---- compute: one element per thread; LDS reads at stride 3 (2 lanes/bank = free) ----
    if (tid < n) {
        float t0 = s_in[0][3*tid+0], t1 = s_in[0][3*tid+1], t2 = s_in[0][3*tid+2];

        float R[9], U[9];
        rodrigues(s_in[1][3*tid+0], s_in[1][3*tid+1], s_in[1][3*tid+2], R);
        rodrigues(s_in[2][3*tid+0], s_in[2][3*tid+1], s_in[2][3*tid+2], U);
        const float d0 = expf(s_in[3][3*tid+0]);
        const float d1 = expf(s_in[3][3*tid+1]);
        const float d2 = expf(s_in[3][3*tid+2]);

        // W = U * diag(d)
        const float W0 = U[0]*d0, W1 = U[1]*d1, W2 = U[2]*d2;
        const float W3 = U[3]*d0, W4 = U[4]*d1, W5 = U[5]*d2;
        const float W6 = U[6]*d0, W7 = U[7]*d1, W8 = U[8]*d2;

        // S = W * U^T (symmetric — fp-identical to full 3x3, verified passing)
        const float S00 = W0*U[0] + W1*U[1] + W2*U[2];
        const float S01 = W0*U[3] + W1*U[4] + W2*U[5];
        const float S02 = W0*U[6] + W1*U[7] + W2*U[8];
        const float S11 = W3*U[3] + W4*U[4] + W5*U[5];
        const float S12 = W3*U[6] + W4*U[7] + W5*U[8];
        const float S22 = W6*U[6] + W7*U[7] + W8*U[8];

        // M = R * S
        const float M00 = R[0]*S00 + R[1]*S01 + R[2]*S02;
        const float M01 = R[0]*S01 + R[1]*S11 + R[2]*S12;
        const float M02 = R[0]*S02 + R[1]*S12 + R[2]*S22;
        const float M10 = R[3]*S00 + R[4]*S01 + R[5]*S02;
        const float M11 = R[3]*S01 + R[4]*S11 + R[5]*S12;
        const float M12 = R[3]*S02 + R[4]*S12 + R[5]*S22;
        const float M20 = R[6]*S00 + R[7]*S01 + R[8]*S02;
        const float M21 = R[6]*S01 + R[7]*S11 + R[8]*S12;
        const float M22 = R[6]*S02 + R[7]*S12 + R[8]*S22;

        // direct stores, nontemporal (evict-first: keep LLC for the input streams)
        float4* o = out + 3 * (base + tid);
        nt_store4(o + 0, M00, M01, M02, t0);
        nt_store4(o + 1, M10, M11, M12, t1);
        nt_store4(o + 2, M20, M21, M22, t2);
    }
}

extern "C" void kernel_launch(void* const* d_in, const int* in_sizes, int n_in,
                              void* d_out, int out_size, void* d_ws, size_t ws_size,
                              hipStream_t stream) {
    int B = in_sizes[0] / 3;                     // 2,000,000 elements
    int blocks = (B + TPB - 1) / TPB;            // 15,625 blocks, no tail for B=2M
    aff_kernel<<<blocks, TPB, 0, stream>>>((const float4*)d_in[0], (const float4*)d_in[1],
                                           (const float4*)d_in[2], (const float4*)d_in[3],
                                           (float4*)d_out, B);
}

// Round 9
// 184.257 us; speedup vs baseline: 1.0533x; 1.0533x over previous
//
#include <hip/hip_runtime.h>
#include <math.h>

#define TPB 256

// 12-byte element record; global load compiles to global_load_dwordx3 (4B-aligned ok)
struct __align__(4) f3 { float x, y, z; };

// R = I + a*K + b*K^2 with K=skew(v), K^2 = v v^T - th^2 I
// => R = (1 - b*th^2) I + b * v v^T + a * K   (matches reference incl. small-angle branch)
__device__ __forceinline__ void rodrigues(float v0, float v1, float v2, float R[9]) {
    float th2 = v0 * v0 + v1 * v1 + v2 * v2;
    float th  = sqrtf(th2);
    float s, c;
    sincosf(th, &s, &c);
    bool  sm = th < 1e-6f;
    float a  = sm ? 1.0f : s / th;
    float b  = sm ? 0.5f : (1.0f - c) / th2;
    float cc = 1.0f - b * th2;
    R[0] = cc + b * v0 * v0;      R[1] = b * v0 * v1 - a * v2;  R[2] = b * v0 * v2 + a * v1;
    R[3] = b * v0 * v1 + a * v2;  R[4] = cc + b * v1 * v1;      R[5] = b * v1 * v2 - a * v0;
    R[6] = b * v0 * v2 - a * v1;  R[7] = b * v1 * v2 + a * v0;  R[8] = cc + b * v2 * v2;
}

// One element -> 3 float4 rows of [M | t], stored directly (48-B lane stride:
// the store pattern R5 proved non-amplifying, WRITE_SIZE exact).
__device__ __forceinline__ void compute_store(
    const f3 t, const f3 r, const f3 u, const f3 s, float4* __restrict__ o)
{
    float R[9], U[9];
    rodrigues(r.x, r.y, r.z, R);
    rodrigues(u.x, u.y, u.z, U);
    const float d0 = expf(s.x), d1 = expf(s.y), d2 = expf(s.z);

    // W = U * diag(d)
    const float W0 = U[0]*d0, W1 = U[1]*d1, W2 = U[2]*d2;
    const float W3 = U[3]*d0, W4 = U[4]*d1, W5 = U[5]*d2;
    const float W6 = U[6]*d0, W7 = U[7]*d1, W8 = U[8]*d2;

    // S = W * U^T (symmetric — fp-identical to full 3x3, verified passing)
    const float S00 = W0*U[0] + W1*U[1] + W2*U[2];
    const float S01 = W0*U[3] + W1*U[4] + W2*U[5];
    const float S02 = W0*U[6] + W1*U[7] + W2*U[8];
    const float S11 = W3*U[3] + W4*U[4] + W5*U[5];
    const float S12 = W3*U[6] + W4*U[7] + W5*U[8];
    const float S22 = W6*U[6] + W7*U[7] + W8*U[8];

    // M = R * S
    const float M00 = R[0]*S00 + R[1]*S01 + R[2]*S02;
    const float M01 = R[0]*S01 + R[1]*S11 + R[2]*S12;
    const float M02 = R[0]*S02 + R[1]*S12 + R[2]*S22;
    const float M10 = R[3]*S00 + R[4]*S01 + R[5]*S02;
    const float M11 = R[3]*S01 + R[4]*S11 + R[5]*S12;
    const float M12 = R[3]*S02 + R[4]*S12 + R[5]*S22;
    const float M20 = R[6]*S00 + R[7]*S01 + R[8]*S02;
    const float M21 = R[6]*S01 + R[7]*S11 + R[8]*S12;
    const float M22 = R[6]*S02 + R[7]*S12 + R[8]*S22;

    o[0] = make_float4(M00, M01, M02, t.x);
    o[1] = make_float4(M10, M11, M12, t.y);
    o[2] = make_float4(M20, M21, M22, t.z);
}

// Barrier-free, LDS-free software pipeline. Each global wave owns 256 consecutive
// elements; lane l owns elements base+64b+l (b=0..3, stride-64 ownership) so:
//   loads : dwordx3/lane, wave instruction covers 768 B contiguous (R1: FETCH-clean)
//   stores: 3x float4/lane at 48-B stride (R5: WRITE-clean)
// Two-slot register pipeline (A: batches 0,2; B: batches 1,3): compute of batch b
// overlaps the in-flight loads of batch b+2. No __syncthreads anywhere -> waves
// are self-paced, memory and VALU phases of different waves interleave instead of
// lockstepping (the diagnosed plateau mechanism of R0/R4/R5).
__global__ __launch_bounds__(TPB) void aff_kernel(
    const f3* __restrict__ trans,
    const f3* __restrict__ rotat,
    const f3* __restrict__ sdir,
    const f3* __restrict__ scal,
    float4* __restrict__ out,
    int B)
{
    const int lane  = threadIdx.x & 63;
    const int wid   = (blockIdx.x * TPB + threadIdx.x) >> 6;  // global wave id
    const int ebase = wid << 8;                               // 256 elements per wave
    if (ebase >= B) return;

    const int e0 = ebase + lane;
    // B % 64 == 0 here, so batch validity is wave-uniform: batch b valid iff ebase+64b < B
    const bool g1 = (ebase +  64) < B;
    const bool g2 = (ebase + 128) < B;
    const bool g3 = (ebase + 192) < B;

    f3 tA, rA, uA, sA;      // slot A: batches 0, 2
    f3 tB, rB, uB, sB;      // slot B: batches 1, 3

    // prime: batches 0 and 1 in flight together
    { const int e = e0;      tA = trans[e]; rA = rotat[e]; uA = sdir[e]; sA = scal[e]; }
    if (g1) { const int e = e0 + 64;  tB = trans[e]; rB = rotat[e]; uB = sdir[e]; sB = scal[e]; }

    compute_store(tA, rA, uA, sA, out + 3 * e0);                    // batch 0
    if (g2) { const int e = e0 + 128; tA = trans[e]; rA = rotat[e]; uA = sdir[e]; sA = scal[e]; }

    if (g1) compute_store(tB, rB, uB, sB, out + 3 * (e0 + 64));     // batch 1
    if (g3) { const int e = e0 + 192; tB = trans[e]; rB = rotat[e]; uB = sdir[e]; sB = scal[e]; }

    if (g2) compute_store(tA, rA, uA, sA, out + 3 * (e0 + 128));    // batch 2
    if (g3) compute_store(tB, rB, uB, sB, out + 3 * (e0 + 192));    // batch 3
}

extern "C" void kernel_launch(void* const* d_in, const int* in_sizes, int n_in,
                              void* d_out, int out_size, void* d_ws, size_t ws_size,
                              hipStream_t stream) {
    int B = in_sizes[0] / 3;                       // 2,000,000 elements
    int waves  = (B + 255) / 256;                  // 7813 element-waves
    int blocks = (waves * 64 + TPB - 1) / TPB;     // 1954 blocks
    aff_kernel<<<blocks, TPB, 0, stream>>>((const f3*)d_in[0], (const f3*)d_in[1],
                                           (const f3*)d_in[2], (const f3*)d_in[3],
                                           (float4*)d_out, B);
}

// Round 10
// 176.604 us; speedup vs baseline: 1.0990x; 1.0433x over previous
//
#include <hip/hip_runtime.h>
#include <math.h>

#define TPB 256

// native clang vector type accepted by __builtin_nontemporal_store
typedef float nt_float4 __attribute__((ext_vector_type(4)));

// R = I + a*K + b*K^2 with K=skew(v), K^2 = v v^T - th^2 I
// => R = (1 - b*th^2) I + b * v v^T + a * K   (matches reference incl. small-angle branch)
__device__ __forceinline__ void rodrigues(float v0, float v1, float v2, float R[9]) {
    float th2 = v0 * v0 + v1 * v1 + v2 * v2;
    float th  = sqrtf(th2);
    float s, c;
    sincosf(th, &s, &c);
    bool  sm = th < 1e-6f;
    float a  = sm ? 1.0f : s / th;
    float b  = sm ? 0.5f : (1.0f - c) / th2;
    float cc = 1.0f - b * th2;
    R[0] = cc + b * v0 * v0;      R[1] = b * v0 * v1 - a * v2;  R[2] = b * v0 * v2 + a * v1;
    R[3] = b * v0 * v1 + a * v2;  R[4] = cc + b * v1 * v1;      R[5] = b * v1 * v2 - a * v0;
    R[6] = b * v0 * v2 - a * v1;  R[7] = b * v1 * v2 + a * v0;  R[8] = cc + b * v2 * v2;
}

// Exact round-0 structure (best measured: 58.5 µs, WRITE_SIZE exact) with ONE change:
// the staged LDS->global output copy uses NONTEMPORAL stores. Rationale (9-round fit):
// dur ≈ hbm_bytes / 2.35 TB/s across all variants; the only reducible bytes are
// FETCH's 47 MB of input re-reads caused by the 94-MB output stream evicting inputs
// from the 256-MB LLC. NT is safe HERE because each wave store instruction writes
// 1 KB contiguous = 16 FULL 64-B lines (no partial-line eviction — the R8 failure
// mode of NT on 48-B-stride combs, which amplified WRITE by +48%).
__global__ __launch_bounds__(TPB) void aff_kernel(
    const float4* __restrict__ trans,
    const float4* __restrict__ rotat,
    const float4* __restrict__ sdir,
    const float4* __restrict__ scal,
    float4* __restrict__ out,
    int B)
{
    __shared__ float s_in[4][TPB * 3];   // 12 KB: 768 floats per input
    __shared__ float s_out[TPB * 12];    // 12 KB: flat output slab (== global layout)

    const int tid  = threadIdx.x;
    const int base = blockIdx.x * TPB;           // first element of this block
    const int n    = min(TPB, B - base);         // elements in this block (256 or tail)
    const int nf4  = (n * 3) >> 2;               // float4s per input (n*3 divisible by 4)

    // ---- coalesced global -> LDS: 192 consecutive float4 per input ----
    if (tid < nf4) {
        const int gbase = (base * 3) >> 2;       // = blockIdx.x * 192
        float4 a = trans[gbase + tid];
        float4 b = rotat[gbase + tid];
        float4 c = sdir [gbase + tid];
        float4 d = scal [gbase + tid];
        ((float4*)&s_in[0][0])[tid] = a;
        ((float4*)&s_in[1][0])[tid] = b;
        ((float4*)&s_in[2][0])[tid] = c;
        ((float4*)&s_in[3][0])[tid] = d;
    }
    __syncthreads();

    // ---- compute: one element per thread; LDS reads at stride 3 (conflict-free) ----
    if (tid < n) {
        float t0 = s_in[0][3*tid+0], t1 = s_in[0][3*tid+1], t2 = s_in[0][3*tid+2];

        float R[9], U[9];
        rodrigues(s_in[1][3*tid+0], s_in[1][3*tid+1], s_in[1][3*tid+2], R);
        rodrigues(s_in[2][3*tid+0], s_in[2][3*tid+1], s_in[2][3*tid+2], U);
        const float d0 = expf(s_in[3][3*tid+0]);
        const float d1 = expf(s_in[3][3*tid+1]);
        const float d2 = expf(s_in[3][3*tid+2]);

        // W = U * diag(d)
        const float W0 = U[0]*d0, W1 = U[1]*d1, W2 = U[2]*d2;
        const float W3 = U[3]*d0, W4 = U[4]*d1, W5 = U[5]*d2;
        const float W6 = U[6]*d0, W7 = U[7]*d1, W8 = U[8]*d2;

        // S = W * U^T (symmetric — fp-identical to full 3x3, verified passing)
        const float S00 = W0*U[0] + W1*U[1] + W2*U[2];
        const float S01 = W0*U[3] + W1*U[4] + W2*U[5];
        const float S02 = W0*U[6] + W1*U[7] + W2*U[8];
        const float S11 = W3*U[3] + W4*U[4] + W5*U[5];
        const float S12 = W3*U[6] + W4*U[7] + W5*U[8];
        const float S22 = W6*U[6] + W7*U[7] + W8*U[8];

        // M = R * S
        const float M00 = R[0]*S00 + R[1]*S01 + R[2]*S02;
        const float M01 = R[0]*S01 + R[1]*S11 + R[2]*S12;
        const float M02 = R[0]*S02 + R[1]*S12 + R[2]*S22;
        const float M10 = R[3]*S00 + R[4]*S01 + R[5]*S02;
        const float M11 = R[3]*S01 + R[4]*S11 + R[5]*S12;
        const float M12 = R[3]*S02 + R[4]*S12 + R[5]*S22;
        const float M20 = R[6]*S00 + R[7]*S01 + R[8]*S02;
        const float M21 = R[6]*S01 + R[7]*S11 + R[8]*S12;
        const float M22 = R[6]*S02 + R[7]*S12 + R[8]*S22;

        // 12 floats -> 3 aligned float4 LDS writes (byte addr 48*tid + 16c)
        float4* so = (float4*)s_out;
        so[3*tid+0] = make_float4(M00, M01, M02, t0);
        so[3*tid+1] = make_float4(M10, M11, M12, t1);
        so[3*tid+2] = make_float4(M20, M21, M22, t2);
    }
    __syncthreads();

    // ---- coalesced LDS -> global, NONTEMPORAL: 768 consecutive float4 per block.
    // Each wave instruction covers 1 KB contiguous (16 full 64-B lines) -> NT cannot
    // create partial-line evictions; it only keeps the output out of the LLC.
    const int nq = n * 3;                        // output float4 count for this block
    const nt_float4* so = (const nt_float4*)s_out;
    nt_float4* og = (nt_float4*)(out + base * 3);
#pragma unroll
    for (int p = 0; p < 3; ++p) {
        int idx = p * TPB + tid;
        if (idx < nq) __builtin_nontemporal_store(so[idx], og + idx);
    }
}

extern "C" void kernel_launch(void* const* d_in, const int* in_sizes, int n_in,
                              void* d_out, int out_size, void* d_ws, size_t ws_size,
                              hipStream_t stream) {
    int B = in_sizes[0] / 3;                     // 2,000,000 elements
    int blocks = (B + TPB - 1) / TPB;            // 7813 blocks
    aff_kernel<<<blocks, TPB, 0, stream>>>((const float4*)d_in[0], (const float4*)d_in[1],
                                           (const float4*)d_in[2], (const float4*)d_in[3],
                                           (float4*)d_out, B);
}